// Round 2
// baseline (207.777 us; speedup 1.0000x reference)
//
#include <hip/hip_runtime.h>
#include <hip/hip_bf16.h>
#include <stdint.h>

// ReplicatorDerivLayer on MI355X. Pipeline:
//  prep_x: x f32 -> xb bf16 [b][e][s] + xbT bf16 [b][s][e]   (one read of x)
//  Wcat = [W1^T ; W2] bf16 [1024][512]
//  Fcat[s][0:512]=F1T, Fcat[s][512:1024]=F2T  (one fused GEMM, M=2048 N=1024 K=512)
//  Wm[s][t] = sum_f F1T[s][f] F2T[t][f], lower-tri tiles only (diag tile masked)
//  fit[e][s] = sum_t xb[e][t] Wm[s][t], split-K chunks + f32 atomics
//  out = relu(x * (1 + fit - avg)),  avg[e] = sum_s x*fit
//
// GEMM: 256x256 tile, BK=64, 8 waves, dbuf LDS (128KB), XOR-swizzled chunks,
// counted vmcnt(8) pipeline with raw s_barrier (no compiler vmcnt(0) drain).

#define SEQ 2048
#define EMB 512
#define NBATCH 8

typedef unsigned short u16;
typedef __bf16 bf16x8 __attribute__((ext_vector_type(8)));
typedef float f32x4 __attribute__((ext_vector_type(4)));
typedef u16 u16x8 __attribute__((ext_vector_type(8)));

#define AS1 __attribute__((address_space(1)))
#define AS3 __attribute__((address_space(3)))

__device__ __forceinline__ u16 f2bf(float f) {
  uint32_t u = __builtin_bit_cast(uint32_t, f);
  uint32_t r = u + 0x7FFFu + ((u >> 16) & 1u);
  return (u16)(r >> 16);
}

__device__ __forceinline__ void gld_lds16(const void* g, void* l) {
  __builtin_amdgcn_global_load_lds((AS1 uint32_t*)g, (AS3 uint32_t*)l, 16, 0, 0);
}

// ---------------- prep_x: one pass producing xb [e][s] and xbT [s][e] ----------------
__global__ __launch_bounds__(256) void prep_x_kernel(const float* __restrict__ x,
    u16* __restrict__ xb, u16* __restrict__ xbT) {
  __shared__ float tile[64][65];
  const int b = blockIdx.z;
  const int s0 = blockIdx.x * 64, e0 = blockIdx.y * 64;
  const float* xin = x + (size_t)b * EMB * SEQ;
  const int tid = threadIdx.x;
  #pragma unroll
  for (int it = 0; it < 4; ++it) {
    int idx = it * 256 + tid;
    int r = idx >> 4, c4 = idx & 15;
    float4 v = *(const float4*)(xin + (size_t)(e0 + r) * SEQ + s0 + c4 * 4);
    tile[r][c4 * 4 + 0] = v.x; tile[r][c4 * 4 + 1] = v.y;
    tile[r][c4 * 4 + 2] = v.z; tile[r][c4 * 4 + 3] = v.w;
  }
  __syncthreads();
  u16* ob = xb + (size_t)b * EMB * SEQ;
  #pragma unroll
  for (int it = 0; it < 2; ++it) {
    int idx = it * 256 + tid; int r = idx >> 3, c8 = idx & 7;
    u16x8 o;
    #pragma unroll
    for (int q = 0; q < 8; ++q) o[q] = f2bf(tile[r][c8 * 8 + q]);
    *(u16x8*)(ob + (size_t)(e0 + r) * SEQ + s0 + c8 * 8) = o;
  }
  u16* obT = xbT + (size_t)b * SEQ * EMB;
  #pragma unroll
  for (int it = 0; it < 2; ++it) {
    int idx = it * 256 + tid; int r = idx >> 3, c8 = idx & 7;
    u16x8 o;
    #pragma unroll
    for (int q = 0; q < 8; ++q) o[q] = f2bf(tile[c8 * 8 + q][r]);
    *(u16x8*)(obT + (size_t)(s0 + r) * EMB + e0 + c8 * 8) = o;
  }
}

// ---------------- small helpers: cast & transpose-cast (weights) ----------------
__global__ __launch_bounds__(256) void cast_bf16_kernel(const float* __restrict__ in,
                                                        u16* __restrict__ out, int n4) {
  int i = blockIdx.x * 256 + threadIdx.x;
  if (i >= n4) return;
  float4 v = reinterpret_cast<const float4*>(in)[i];
  ushort4 r;
  r.x = f2bf(v.x); r.y = f2bf(v.y); r.z = f2bf(v.z); r.w = f2bf(v.w);
  reinterpret_cast<ushort4*>(out)[i] = r;
}

__global__ __launch_bounds__(256) void transpose_cast_kernel(const float* __restrict__ in,
    u16* __restrict__ out, int R, int C) {
  __shared__ float tile[32][33];
  const int c0 = blockIdx.x * 32, r0 = blockIdx.y * 32;
  const int tx = threadIdx.x, ty = threadIdx.y;  // (32, 8)
  #pragma unroll
  for (int i = 0; i < 32; i += 8)
    tile[ty + i][tx] = in[(size_t)(r0 + ty + i) * C + c0 + tx];
  __syncthreads();
  #pragma unroll
  for (int i = 0; i < 32; i += 8)
    out[(size_t)(c0 + ty + i) * R + r0 + tx] = f2bf(tile[tx][ty + i]);
}

__global__ __launch_bounds__(256) void clear_kernel(float4* __restrict__ p, int n4) {
  int i = blockIdx.x * 256 + threadIdx.x;
  if (i < n4) p[i] = (float4){0.f, 0.f, 0.f, 0.f};
}

// ---------------- 256x256 pipelined bt-GEMM: C[m][n] = sum_k A[m][k] B[n][k] ----------------
// MODE 0: plain, bf16 out (projcat).
// MODE 1: lower-tri tile grid (blockIdx.x = linear tri idx), mask n>m on diag tile, bf16 out.
// MODE 2: split-K chunks (blockIdx.x encodes (ntile j, chunk c)), f32 atomicAdd out.
template<int MODE>
__global__ __launch_bounds__(512, 2) void gemm8_kernel(
    const u16* __restrict__ Ag, const u16* __restrict__ Bg, void* __restrict__ Cg,
    int ldA, int ldB, int ldC, long sA, long sB, long sC, int Kfull) {
  const int tid  = threadIdx.x;
  const int lane = tid & 63;
  const int wave = tid >> 6;
  const int wr = wave >> 2;       // 0..1  (M half)
  const int wc = wave & 3;        // 0..3  (N quarter)
  const int bz = blockIdx.z;

  int bm, bn, k0, kend;
  if (MODE == 0) {
    bm = blockIdx.y; bn = blockIdx.x; k0 = 0; kend = Kfull;
  } else if (MODE == 1) {
    int L = blockIdx.x, i = 0;
    while (L >= i + 1) { L -= i + 1; ++i; }
    bm = i; bn = L; k0 = 0; kend = Kfull;
  } else {
    int L = blockIdx.x, j = 0;
    while (true) { int cnt = (j >> 1) + 1; if (L < cnt) break; L -= cnt; ++j; }
    bm = blockIdx.y; bn = j;
    k0 = L * 512;
    int cap = (j + 1) * 256;
    kend = ((L + 1) * 512 < cap) ? (L + 1) * 512 : cap;
  }
  const int nk = (kend - k0) >> 6;

  const u16* Ab = Ag + (size_t)bz * sA + (size_t)(bm * 256) * ldA;
  const u16* Bb = Bg + (size_t)bz * sB + (size_t)(bn * 256) * ldB;

  __shared__ __align__(16) u16 LA[2][256 * 64];
  __shared__ __align__(16) u16 LB[2][256 * 64];

  const int wbase = wave * 64;  // wave-uniform chunk base within each 512-chunk group

  // stage one 256x64 K-tile of A and B into buffer `sel`.
  // LDS dest linear (chunk L at byte L*16); global source column pre-swizzled
  // (cs = cc ^ (row&7)) so the swizzled ds_read below sees matching data.
  auto stage = [&](int kg, int sel) {
    #pragma unroll
    for (int j = 0; j < 4; ++j) {
      int L = j * 512 + tid;
      int row = L >> 3, cc = L & 7;
      int cs = cc ^ (row & 7);
      gld_lds16(Ab + (size_t)row * ldA + kg + cs * 8, &LA[sel][(size_t)(j * 512 + wbase) * 8]);
    }
    #pragma unroll
    for (int j = 0; j < 4; ++j) {
      int L = j * 512 + tid;
      int row = L >> 3, cc = L & 7;
      int cs = cc ^ (row & 7);
      gld_lds16(Bb + (size_t)row * ldB + kg + cs * 8, &LB[sel][(size_t)(j * 512 + wbase) * 8]);
    }
  };

  f32x4 acc[8][4];
  #pragma unroll
  for (int i = 0; i < 8; ++i)
    #pragma unroll
    for (int j = 0; j < 4; ++j) acc[i][j] = (f32x4){0.f, 0.f, 0.f, 0.f};

  stage(k0, 0);
  stage(k0 + 64, 1);

  const int ar = lane & 15;       // row-in-fragment
  const int asel = lane >> 4;     // k sub-chunk

  auto ldfrag = [&](const u16* base, int rloc, int c2) -> bf16x8 {
    int cs = c2 ^ (rloc & 7);
    return *reinterpret_cast<const bf16x8*>(base + (size_t)(rloc * 8 + cs) * 8);
  };

  for (int kt = 0; kt < nk; ++kt) {
    const int sel = kt & 1;
    if (kt < nk - 1) asm volatile("s_waitcnt vmcnt(8)" ::: "memory");
    else             asm volatile("s_waitcnt vmcnt(0)" ::: "memory");
    __builtin_amdgcn_s_barrier();
    __builtin_amdgcn_sched_barrier(0);

    const u16* a_ = LA[sel];
    const u16* b_ = LB[sel];

    bf16x8 bf_[4][2], af_[4][2];
    #pragma unroll
    for (int n = 0; n < 4; ++n)
      #pragma unroll
      for (int kk = 0; kk < 2; ++kk)
        bf_[n][kk] = ldfrag(b_, wc * 64 + n * 16 + ar, kk * 4 + asel);
    #pragma unroll
    for (int m = 0; m < 4; ++m)
      #pragma unroll
      for (int kk = 0; kk < 2; ++kk)
        af_[m][kk] = ldfrag(a_, wr * 128 + m * 16 + ar, kk * 4 + asel);

    __builtin_amdgcn_s_setprio(1);
    #pragma unroll
    for (int m = 0; m < 4; ++m)
      #pragma unroll
      for (int n = 0; n < 4; ++n)
        #pragma unroll
        for (int kk = 0; kk < 2; ++kk)
          acc[m][n] = __builtin_amdgcn_mfma_f32_16x16x32_bf16(af_[m][kk], bf_[n][kk], acc[m][n], 0, 0, 0);
    __builtin_amdgcn_s_setprio(0);

    #pragma unroll
    for (int m = 0; m < 4; ++m)
      #pragma unroll
      for (int kk = 0; kk < 2; ++kk)
        af_[m][kk] = ldfrag(a_, wr * 128 + 64 + m * 16 + ar, kk * 4 + asel);

    // all LDS reads of this buffer done -> publish -> safe to overwrite it
    asm volatile("s_waitcnt lgkmcnt(0)" ::: "memory");
    __builtin_amdgcn_sched_barrier(0);
    __builtin_amdgcn_s_barrier();
    __builtin_amdgcn_sched_barrier(0);
    if (kt + 2 < nk) stage(k0 + (kt + 2) * 64, sel);

    __builtin_amdgcn_s_setprio(1);
    #pragma unroll
    for (int m = 0; m < 4; ++m)
      #pragma unroll
      for (int n = 0; n < 4; ++n)
        #pragma unroll
        for (int kk = 0; kk < 2; ++kk)
          acc[m + 4][n] = __builtin_amdgcn_mfma_f32_16x16x32_bf16(af_[m][kk], bf_[n][kk], acc[m + 4][n], 0, 0, 0);
    __builtin_amdgcn_s_setprio(0);
  }

  // epilogue: D mapping col = lane&15, row = (lane>>4)*4 + r
  const int r0 = (lane >> 4) * 4;
  const int cn = lane & 15;
  #pragma unroll
  for (int i = 0; i < 8; ++i) {
    const int mrow = (i & 3) * 16 + (i >> 2) * 64;  // acc[i] row offset in wave tile
    #pragma unroll
    for (int j = 0; j < 4; ++j) {
      const int gcol = bn * 256 + wc * 64 + j * 16 + cn;
      #pragma unroll
      for (int r = 0; r < 4; ++r) {
        const int grow = bm * 256 + wr * 128 + mrow + r0 + r;
        float v = acc[i][j][r];
        if (MODE == 2) {
          atomicAdd((float*)Cg + (size_t)bz * sC + (size_t)grow * ldC + gcol, v);
        } else {
          if (MODE == 1 && bm == bn && gcol > grow) v = 0.f;
          ((u16*)Cg)[(size_t)bz * sC + (size_t)grow * ldC + gcol] = f2bf(v);
        }
      }
    }
  }
}

// ---------------- finalize: avg-reduce + elementwise + relu ----------------
__global__ __launch_bounds__(256) void finalize_kernel(const float* __restrict__ x,
    const float* __restrict__ fit, float* __restrict__ out) {
  const size_t row = blockIdx.x;  // b*EMB + e
  const float* xr = x + row * SEQ;
  const float* fr = fit + row * SEQ;
  float* orow = out + row * SEQ;
  const int tid = threadIdx.x;

  float4 xv[2], fv[2];
  float part = 0.f;
  #pragma unroll
  for (int i = 0; i < 2; ++i) {
    xv[i] = reinterpret_cast<const float4*>(xr)[i * 256 + tid];
    fv[i] = reinterpret_cast<const float4*>(fr)[i * 256 + tid];
    part += xv[i].x * fv[i].x + xv[i].y * fv[i].y + xv[i].z * fv[i].z + xv[i].w * fv[i].w;
  }
  #pragma unroll
  for (int off = 1; off < 64; off <<= 1) part += __shfl_xor(part, off);
  __shared__ float wsum[4];
  const int wave = tid >> 6, lane = tid & 63;
  if (lane == 0) wsum[wave] = part;
  __syncthreads();
  const float avg = wsum[0] + wsum[1] + wsum[2] + wsum[3];

  #pragma unroll
  for (int i = 0; i < 2; ++i) {
    float4 o;
    o.x = xv[i].x * (1.f + fv[i].x - avg); o.x = o.x > 0.f ? o.x : 0.f;
    o.y = xv[i].y * (1.f + fv[i].y - avg); o.y = o.y > 0.f ? o.y : 0.f;
    o.z = xv[i].z * (1.f + fv[i].z - avg); o.z = o.z > 0.f ? o.z : 0.f;
    o.w = xv[i].w * (1.f + fv[i].w - avg); o.w = o.w > 0.f ? o.w : 0.f;
    reinterpret_cast<float4*>(orow)[i * 256 + tid] = o;
  }
}

extern "C" void kernel_launch(void* const* d_in, const int* in_sizes, int n_in,
                              void* d_out, int out_size, void* d_ws, size_t ws_size,
                              hipStream_t stream) {
  const float* x  = (const float*)d_in[0];
  const float* W1 = (const float*)d_in[1];
  const float* W2 = (const float*)d_in[2];
  float* out = (float*)d_out;

  char* ws = (char*)d_ws;
  const size_t nX = (size_t)NBATCH * EMB * SEQ;  // 8,388,608

  size_t off = 0;
  u16* xb   = (u16*)(ws + off); off += nX * 2;                         // 16 MB
  const size_t offFit = off;                                           // fit aliases xbT+Wcat+Fcat head
  u16* xbT  = (u16*)(ws + off); off += nX * 2;                         // 16 MB (dead after projcat)
  u16* Wcat = (u16*)(ws + off); off += (size_t)1024 * 512 * 2;         // 1 MB  (dead after projcat)
  u16* Fcat = (u16*)(ws + off); off += (size_t)NBATCH * SEQ * 1024 * 2;// 32 MB (dead after Gram)
  u16* Wm   = (u16*)(ws + off); off += (size_t)NBATCH * SEQ * SEQ * 2; // 64 MB
  float* fit = (float*)(ws + offFit);                                  // 32 MB, written after Gram
  // total: 129 MiB

  // 1) prep
  prep_x_kernel<<<dim3(SEQ / 64, EMB / 64, NBATCH), 256, 0, stream>>>(x, xb, xbT);
  transpose_cast_kernel<<<dim3(EMB / 32, EMB / 32), dim3(32, 8), 0, stream>>>(W1, Wcat, EMB, EMB);
  cast_bf16_kernel<<<EMB * EMB / 4 / 256, 256, 0, stream>>>(W2, Wcat + (size_t)512 * 512, EMB * EMB / 4);

  // 2) fused projections: Fcat[s][n] = sum_k xbT[s][k] * Wcat[n][k]
  gemm8_kernel<0><<<dim3(4, 8, NBATCH), 512, 0, stream>>>(
      xbT, Wcat, Fcat, EMB, EMB, 1024, (long)SEQ * EMB, 0, (long)SEQ * 1024, EMB);

  // 3) Gram lower-tri: Wm[s][t] = sum_f F1T[s][f] F2T[t][f]
  gemm8_kernel<1><<<dim3(36, 1, NBATCH), 512, 0, stream>>>(
      Fcat, Fcat + 512, Wm, 1024, 1024, SEQ, (long)SEQ * 1024, (long)SEQ * 1024, (long)SEQ * SEQ, EMB);

  // 4) fitness: fit[e][s] = sum_t xb[e][t] Wm[s][t]  (split-K + atomics)
  clear_kernel<<<(int)(nX / 4 / 256), 256, 0, stream>>>((float4*)fit, (int)(nX / 4));
  gemm8_kernel<2><<<dim3(20, 2, NBATCH), 512, 0, stream>>>(
      xb, Wm, fit, SEQ, SEQ, SEQ, (long)EMB * SEQ, (long)SEQ * SEQ, (long)EMB * SEQ, SEQ);

  // 5) finalize
  finalize_kernel<<<NBATCH * EMB, 256, 0, stream>>>(x, fit, out);
}

// Round 3
// 142.058 us; speedup vs baseline: 1.4626x; 1.4626x over previous
//
#include <hip/hip_runtime.h>
#include <hip/hip_bf16.h>
#include <stdint.h>

// ReplicatorDerivLayer on MI355X. Pipeline:
//  prep_x: x f32 -> xb bf16 [b][e][s] + xbT bf16 [b][s][e]
//  Wcat = [W1^T ; W2] bf16 [1024][512]
//  Fcat[s][0:512]=F1T, Fcat[s][512:1024]=F2T  (fused GEMM M=2048 N=1024 K=512)
//  Wm[s][t] = sum_f F1T[s][f] F2T[t][f], lower-tri tiles only (diag masked)
//  fit[e][s] = sum_t xb[e][t] Wm[s][t]  (chunked split-K, plain stores, no atomics)
//  out = relu(x * (1 + fit - avg)),  avg[e] = sum_s x*fit   (sums fit + partials)
//
// GEMM: 256x256 tile, BK=64, 8 waves, 4-phase/K-tile schedule (16 MFMA/phase),
// half-tile granular staging, counted vmcnt(4) once per K-tile, XOR-swizzled LDS.

#define SEQ 2048
#define EMB 512
#define NBATCH 8

typedef unsigned short u16;
typedef __bf16 bf16x8 __attribute__((ext_vector_type(8)));
typedef float f32x4 __attribute__((ext_vector_type(4)));
typedef u16 u16x8 __attribute__((ext_vector_type(8)));

#define AS1 __attribute__((address_space(1)))
#define AS3 __attribute__((address_space(3)))

#define SBAR do { __builtin_amdgcn_sched_barrier(0); __builtin_amdgcn_s_barrier(); \
                  __builtin_amdgcn_sched_barrier(0); } while (0)
#define LGKM0 do { asm volatile("s_waitcnt lgkmcnt(0)" ::: "memory"); \
                   __builtin_amdgcn_sched_barrier(0); } while (0)

__device__ __forceinline__ u16 f2bf(float f) {
  uint32_t u = __builtin_bit_cast(uint32_t, f);
  uint32_t r = u + 0x7FFFu + ((u >> 16) & 1u);
  return (u16)(r >> 16);
}

__device__ __forceinline__ void gld_lds16(const void* g, void* l) {
  __builtin_amdgcn_global_load_lds((AS1 uint32_t*)g, (AS3 uint32_t*)l, 16, 0, 0);
}

// ---------------- prep_x: xb [e][s] and xbT [s][e] in one pass ----------------
__global__ __launch_bounds__(256) void prep_x_kernel(const float* __restrict__ x,
    u16* __restrict__ xb, u16* __restrict__ xbT) {
  __shared__ float tile[64][65];
  const int b = blockIdx.z;
  const int s0 = blockIdx.x * 64, e0 = blockIdx.y * 64;
  const float* xin = x + (size_t)b * EMB * SEQ;
  const int tid = threadIdx.x;
  #pragma unroll
  for (int it = 0; it < 4; ++it) {
    int idx = it * 256 + tid;
    int r = idx >> 4, c4 = idx & 15;
    float4 v = *(const float4*)(xin + (size_t)(e0 + r) * SEQ + s0 + c4 * 4);
    tile[r][c4 * 4 + 0] = v.x; tile[r][c4 * 4 + 1] = v.y;
    tile[r][c4 * 4 + 2] = v.z; tile[r][c4 * 4 + 3] = v.w;
  }
  __syncthreads();
  u16* ob = xb + (size_t)b * EMB * SEQ;
  #pragma unroll
  for (int it = 0; it < 2; ++it) {
    int idx = it * 256 + tid; int r = idx >> 3, c8 = idx & 7;
    u16x8 o;
    #pragma unroll
    for (int q = 0; q < 8; ++q) o[q] = f2bf(tile[r][c8 * 8 + q]);
    *(u16x8*)(ob + (size_t)(e0 + r) * SEQ + s0 + c8 * 8) = o;
  }
  u16* obT = xbT + (size_t)b * SEQ * EMB;
  #pragma unroll
  for (int it = 0; it < 2; ++it) {
    int idx = it * 256 + tid; int r = idx >> 3, c8 = idx & 7;
    u16x8 o;
    #pragma unroll
    for (int q = 0; q < 8; ++q) o[q] = f2bf(tile[c8 * 8 + q][r]);
    *(u16x8*)(obT + (size_t)(s0 + r) * EMB + e0 + c8 * 8) = o;
  }
}

__global__ __launch_bounds__(256) void cast_bf16_kernel(const float* __restrict__ in,
                                                        u16* __restrict__ out, int n4) {
  int i = blockIdx.x * 256 + threadIdx.x;
  if (i >= n4) return;
  float4 v = reinterpret_cast<const float4*>(in)[i];
  ushort4 r;
  r.x = f2bf(v.x); r.y = f2bf(v.y); r.z = f2bf(v.z); r.w = f2bf(v.w);
  reinterpret_cast<ushort4*>(out)[i] = r;
}

__global__ __launch_bounds__(256) void transpose_cast_kernel(const float* __restrict__ in,
    u16* __restrict__ out, int R, int C) {
  __shared__ float tile[32][33];
  const int c0 = blockIdx.x * 32, r0 = blockIdx.y * 32;
  const int tx = threadIdx.x, ty = threadIdx.y;  // (32, 8)
  #pragma unroll
  for (int i = 0; i < 32; i += 8)
    tile[ty + i][tx] = in[(size_t)(r0 + ty + i) * C + c0 + tx];
  __syncthreads();
  #pragma unroll
  for (int i = 0; i < 32; i += 8)
    out[(size_t)(c0 + ty + i) * R + r0 + tx] = f2bf(tile[tx][ty + i]);
}

// ---------------- 256x256 8-phase bt-GEMM: C[m][n] = sum_k A[m][k] B[n][k] ----------------
// MODE 0: plain, bf16 out. MODE 1: lower-tri grid, diag mask, bf16 out.
// MODE 2: chunked split-K (15 slots), f32 stores to fit / fitP / fitP2.
template<int MODE>
__global__ __launch_bounds__(512, 2) void gemm8_kernel(
    const u16* __restrict__ Ag, const u16* __restrict__ Bg, void* __restrict__ Cg,
    float* __restrict__ P1out, float* __restrict__ P2out,
    int ldA, int ldB, int ldC, long sA, long sB, long sC, int Kfull) {
  const int tid  = threadIdx.x;
  const int lane = tid & 63;
  const int wave = tid >> 6;
  const int wr = wave >> 2;       // 0..1  (M half)
  const int wc = wave & 3;        // 0..3  (N quarter)
  const int bz = blockIdx.z;

  int bm, bn, k0, kend, dest = 0;
  if (MODE == 0) {
    bm = blockIdx.y; bn = blockIdx.x; k0 = 0; kend = Kfull;
  } else if (MODE == 1) {
    int L = blockIdx.x, i = 0;
    while (L >= i + 1) { L -= i + 1; ++i; }
    bm = i; bn = L; k0 = 0; kend = Kfull;
  } else {
    static const int tj[15]  = {0,1,2,3,3,4,4,5,5,6,6,6,7,7,7};
    static const int tk0[15] = {0,0,0,0,768,0,768,0,768,0,768,1536,0,768,1536};
    static const int tk1[15] = {256,512,768,768,1024,768,1280,768,1536,768,1536,1792,768,1536,2048};
    static const int tds[15] = {0,0,0,0,1,0,1,0,1,0,1,2,0,1,2};
    const int L = blockIdx.x;
    bm = blockIdx.y; bn = tj[L]; k0 = tk0[L]; kend = tk1[L]; dest = tds[L];
  }
  const int nk = (kend - k0) >> 6;

  const u16* Ab = Ag + (size_t)bz * sA + (size_t)(bm * 256) * ldA;
  const u16* Bb = Bg + (size_t)bz * sB + (size_t)(bn * 256) * ldB;

  // 2 dbuf x (2 halves x 128 rows x 64 cols) per operand = 128 KiB
  __shared__ __align__(16) u16 LA[2][256 * 64];
  __shared__ __align__(16) u16 LB[2][256 * 64];

  // stage one half-tile (128 rows x 64 bf16 = 16KB): 2 loads/thread, linear LDS,
  // inverse-swizzled global source column (cs = cc ^ (row&7)).
  auto stage_half = [&](const u16* gbase, int ldG, int rowOff, int kcol, u16* lds) {
    #pragma unroll
    for (int p = 0; p < 2; ++p) {
      int c = p * 512 + tid;              // chunk 0..1023
      int row = c >> 3, cc = c & 7;
      int cs = cc ^ (row & 7);
      gld_lds16(gbase + (size_t)(rowOff + row) * ldG + kcol + cs * 8,
                lds + (size_t)(p * 512 + wave * 64) * 8);
    }
  };

  // swizzled fragment read: row rloc (0..255 in tile), col-group c2 (0..7)
  auto ldfrag = [&](const u16* base, int rloc, int c2) -> bf16x8 {
    int cs = c2 ^ (rloc & 7);
    return *reinterpret_cast<const bf16x8*>(base + (size_t)(rloc * 8 + cs) * 8);
  };

  f32x4 acc[8][4];
  #pragma unroll
  for (int i = 0; i < 8; ++i)
    #pragma unroll
    for (int j = 0; j < 4; ++j) acc[i][j] = (f32x4){0.f, 0.f, 0.f, 0.f};

  // prologue stage order (vmcnt counting depends on it!):
  // 0.A0, 0.A1, 0.B0, 0.B1, [1.B0, 1.B1]
  stage_half(Ab, ldA, 0,   k0, LA[0]);
  stage_half(Ab, ldA, 128, k0, LA[0] + 8192);
  stage_half(Bb, ldB, 0,   k0, LB[0]);
  stage_half(Bb, ldB, 128, k0, LB[0] + 8192);
  if (nk > 1) {
    stage_half(Bb, ldB, 0,   k0 + 64, LB[1]);
    stage_half(Bb, ldB, 128, k0 + 64, LB[1] + 8192);
  }
  if (nk > 1) { asm volatile("s_waitcnt vmcnt(4)" ::: "memory"); }
  else        { asm volatile("s_waitcnt vmcnt(0)" ::: "memory"); }
  SBAR;

  const int ar = lane & 15;
  const int asel = lane >> 4;

  bf16x8 af[4][2], bf0[2][2], bf1[2][2];

  for (int t = 0; t < nk; ++t) {
    const int sel = t & 1;
    const u16* a_ = LA[sel];
    const u16* b_ = LB[sel];

    // ---- P1: read A[m0-3], B[n0-1]; stage (t+1).A-h0; MFMA mA x nA ----
    #pragma unroll
    for (int m = 0; m < 4; ++m)
      #pragma unroll
      for (int kk = 0; kk < 2; ++kk)
        af[m][kk] = ldfrag(a_, wr * 128 + m * 16 + ar, kk * 4 + asel);
    #pragma unroll
    for (int n = 0; n < 2; ++n)
      #pragma unroll
      for (int kk = 0; kk < 2; ++kk)
        bf0[n][kk] = ldfrag(b_, wc * 64 + n * 16 + ar, kk * 4 + asel);
    if (t + 1 < nk) stage_half(Ab, ldA, 0, k0 + (t + 1) * 64, LA[sel ^ 1]);
    SBAR; LGKM0;
    __builtin_amdgcn_s_setprio(1);
    #pragma unroll
    for (int m = 0; m < 4; ++m)
      #pragma unroll
      for (int n = 0; n < 2; ++n)
        #pragma unroll
        for (int kk = 0; kk < 2; ++kk)
          acc[m][n] = __builtin_amdgcn_mfma_f32_16x16x32_bf16(af[m][kk], bf0[n][kk], acc[m][n], 0, 0, 0);
    __builtin_amdgcn_s_setprio(0);
    SBAR;

    // ---- P2: read B[n2-3]; stage (t+1).A-h1; MFMA mA x nB ----
    #pragma unroll
    for (int n = 0; n < 2; ++n)
      #pragma unroll
      for (int kk = 0; kk < 2; ++kk)
        bf1[n][kk] = ldfrag(b_, wc * 64 + (n + 2) * 16 + ar, kk * 4 + asel);
    if (t + 1 < nk) stage_half(Ab, ldA, 128, k0 + (t + 1) * 64, LA[sel ^ 1] + 8192);
    SBAR; LGKM0;
    __builtin_amdgcn_s_setprio(1);
    #pragma unroll
    for (int m = 0; m < 4; ++m)
      #pragma unroll
      for (int n = 0; n < 2; ++n)
        #pragma unroll
        for (int kk = 0; kk < 2; ++kk)
          acc[m][n + 2] = __builtin_amdgcn_mfma_f32_16x16x32_bf16(af[m][kk], bf1[n][kk], acc[m][n + 2], 0, 0, 0);
    __builtin_amdgcn_s_setprio(0);
    SBAR;

    // ---- P3: read A[m4-7]; stage (t+2).B-h0; MFMA mB x nB ----
    #pragma unroll
    for (int m = 0; m < 4; ++m)
      #pragma unroll
      for (int kk = 0; kk < 2; ++kk)
        af[m][kk] = ldfrag(a_, wr * 128 + 64 + m * 16 + ar, kk * 4 + asel);
    if (t + 2 < nk) stage_half(Bb, ldB, 0, k0 + (t + 2) * 64, LB[sel]);
    SBAR; LGKM0;
    __builtin_amdgcn_s_setprio(1);
    #pragma unroll
    for (int m = 0; m < 4; ++m)
      #pragma unroll
      for (int n = 0; n < 2; ++n)
        #pragma unroll
        for (int kk = 0; kk < 2; ++kk)
          acc[m + 4][n + 2] = __builtin_amdgcn_mfma_f32_16x16x32_bf16(af[m][kk], bf1[n][kk], acc[m + 4][n + 2], 0, 0, 0);
    __builtin_amdgcn_s_setprio(0);
    SBAR;

    // ---- P4: stage (t+2).B-h1; MFMA mB x nA; counted vmcnt for next tile ----
    if (t + 2 < nk) stage_half(Bb, ldB, 128, k0 + (t + 2) * 64, LB[sel] + 8192);
    SBAR;
    __builtin_amdgcn_s_setprio(1);
    #pragma unroll
    for (int m = 0; m < 4; ++m)
      #pragma unroll
      for (int n = 0; n < 2; ++n)
        #pragma unroll
        for (int kk = 0; kk < 2; ++kk)
          acc[m + 4][n] = __builtin_amdgcn_mfma_f32_16x16x32_bf16(af[m][kk], bf0[n][kk], acc[m + 4][n], 0, 0, 0);
    __builtin_amdgcn_s_setprio(0);
    // certify next tile's halves (own loads), barrier makes it collective
    if (t + 1 < nk) {
      if (t + 2 < nk) { asm volatile("s_waitcnt vmcnt(4)" ::: "memory"); }
      else            { asm volatile("s_waitcnt vmcnt(0)" ::: "memory"); }
    }
    SBAR;
  }

  // epilogue: D mapping col = lane&15, row = (lane>>4)*4 + r
  const int r0 = (lane >> 4) * 4;
  const int cn = lane & 15;
  #pragma unroll
  for (int m = 0; m < 8; ++m) {
    #pragma unroll
    for (int n = 0; n < 4; ++n) {
      const int gcol = bn * 256 + wc * 64 + n * 16 + cn;
      #pragma unroll
      for (int r = 0; r < 4; ++r) {
        const int grow = bm * 256 + wr * 128 + m * 16 + r0 + r;
        float v = acc[m][n][r];
        if (MODE == 2) {
          float* base; int ldc, coff;
          if (dest == 0)      { base = (float*)Cg + (size_t)bz * sC; ldc = SEQ;  coff = 0; }
          else if (dest == 1) { base = P1out + (size_t)bz * (512 * 1280); ldc = 1280; coff = 768; }
          else                { base = P2out + (size_t)bz * (512 * 512);  ldc = 512;  coff = 1536; }
          base[(size_t)grow * ldc + (gcol - coff)] = v;
        } else {
          if (MODE == 1 && bm == bn && gcol > grow) v = 0.f;
          ((u16*)Cg)[(size_t)bz * sC + (size_t)grow * ldC + gcol] = f2bf(v);
        }
      }
    }
  }
}

// ---------------- finalize: fit = fit + partials; avg-reduce; relu ----------------
__global__ __launch_bounds__(256) void finalize_kernel(const float* __restrict__ x,
    const float* __restrict__ fit, const float* __restrict__ fitP,
    const float* __restrict__ fitP2, float* __restrict__ out) {
  const size_t row = blockIdx.x;  // b*EMB + e
  const float* xr = x + row * SEQ;
  const float* fr = fit + row * SEQ;
  const float* p1 = fitP + row * 1280;   // s in [768, 2048)
  const float* p2 = fitP2 + row * 512;   // s in [1536, 2048)
  float* orow = out + row * SEQ;
  const int tid = threadIdx.x;

  float4 xv[2], fv[2];
  float part = 0.f;
  #pragma unroll
  for (int i = 0; i < 2; ++i) {
    const int s0 = i * 1024 + tid * 4;
    xv[i] = reinterpret_cast<const float4*>(xr)[i * 256 + tid];
    fv[i] = reinterpret_cast<const float4*>(fr)[i * 256 + tid];
    if (s0 >= 768) {
      float4 a = *reinterpret_cast<const float4*>(p1 + (s0 - 768));
      fv[i].x += a.x; fv[i].y += a.y; fv[i].z += a.z; fv[i].w += a.w;
    }
    if (s0 >= 1536) {
      float4 a = *reinterpret_cast<const float4*>(p2 + (s0 - 1536));
      fv[i].x += a.x; fv[i].y += a.y; fv[i].z += a.z; fv[i].w += a.w;
    }
    part += xv[i].x * fv[i].x + xv[i].y * fv[i].y + xv[i].z * fv[i].z + xv[i].w * fv[i].w;
  }
  #pragma unroll
  for (int off = 1; off < 64; off <<= 1) part += __shfl_xor(part, off);
  __shared__ float wsum[4];
  const int wave = tid >> 6, lane = tid & 63;
  if (lane == 0) wsum[wave] = part;
  __syncthreads();
  const float avg = wsum[0] + wsum[1] + wsum[2] + wsum[3];

  #pragma unroll
  for (int i = 0; i < 2; ++i) {
    float4 o;
    o.x = xv[i].x * (1.f + fv[i].x - avg); o.x = o.x > 0.f ? o.x : 0.f;
    o.y = xv[i].y * (1.f + fv[i].y - avg); o.y = o.y > 0.f ? o.y : 0.f;
    o.z = xv[i].z * (1.f + fv[i].z - avg); o.z = o.z > 0.f ? o.z : 0.f;
    o.w = xv[i].w * (1.f + fv[i].w - avg); o.w = o.w > 0.f ? o.w : 0.f;
    reinterpret_cast<float4*>(orow)[i * 256 + tid] = o;
  }
}

extern "C" void kernel_launch(void* const* d_in, const int* in_sizes, int n_in,
                              void* d_out, int out_size, void* d_ws, size_t ws_size,
                              hipStream_t stream) {
  const float* x  = (const float*)d_in[0];
  const float* W1 = (const float*)d_in[1];
  const float* W2 = (const float*)d_in[2];
  float* out = (float*)d_out;

  char* ws = (char*)d_ws;
  const size_t nX = (size_t)NBATCH * EMB * SEQ;  // 8,388,608

  size_t off = 0;
  u16* xb   = (u16*)(ws + off); off += nX * 2;                          // 16 MB
  const size_t offFit = off;                                            // fit aliases xbT+Wcat+Fcat
  u16* xbT  = (u16*)(ws + off); off += nX * 2;                          // 16 MB (dead after projcat)
  u16* Wcat = (u16*)(ws + off); off += (size_t)1024 * 512 * 2;          // 1 MB  (dead after projcat)
  u16* Fcat = (u16*)(ws + off); off += (size_t)NBATCH * SEQ * 1024 * 2; // 32 MB (dead after Gram)
  u16* Wm   = (u16*)(ws + off); off += (size_t)NBATCH * SEQ * SEQ * 2;  // 64 MB
  float* fitP  = (float*)(ws + off); off += (size_t)NBATCH * 512 * 1280 * 4; // 21 MB
  float* fitP2 = (float*)(ws + off); off += (size_t)NBATCH * 512 * 512 * 4;  // 8.4 MB
  float* fit = (float*)(ws + offFit);                                   // 33.5 MB
  // total: ~157 MiB

  // 1) prep
  prep_x_kernel<<<dim3(SEQ / 64, EMB / 64, NBATCH), 256, 0, stream>>>(x, xb, xbT);
  transpose_cast_kernel<<<dim3(EMB / 32, EMB / 32), dim3(32, 8), 0, stream>>>(W1, Wcat, EMB, EMB);
  cast_bf16_kernel<<<EMB * EMB / 4 / 256, 256, 0, stream>>>(W2, Wcat + (size_t)512 * 512, EMB * EMB / 4);

  // 2) fused projections: Fcat[s][n] = sum_k xbT[s][k] * Wcat[n][k]
  gemm8_kernel<0><<<dim3(4, 8, NBATCH), 512, 0, stream>>>(
      xbT, Wcat, Fcat, nullptr, nullptr, EMB, EMB, 1024, (long)SEQ * EMB, 0, (long)SEQ * 1024, EMB);

  // 3) Gram lower-tri: Wm[s][t] = sum_f F1T[s][f] F2T[t][f]
  gemm8_kernel<1><<<dim3(36, 1, NBATCH), 512, 0, stream>>>(
      Fcat, Fcat + 512, Wm, nullptr, nullptr, 1024, 1024, SEQ,
      (long)SEQ * 1024, (long)SEQ * 1024, (long)SEQ * SEQ, EMB);

  // 4) fitness: fit[e][s] = sum_t xb[e][t] Wm[s][t]  (chunked split-K, no atomics)
  gemm8_kernel<2><<<dim3(15, 2, NBATCH), 512, 0, stream>>>(
      xb, Wm, fit, fitP, fitP2, SEQ, SEQ, SEQ,
      (long)EMB * SEQ, (long)SEQ * SEQ, (long)EMB * SEQ, SEQ);

  // 5) finalize (sums fit + fitP + fitP2, computes avg, relu)
  finalize_kernel<<<NBATCH * EMB, 256, 0, stream>>>(x, fit, fitP, fitP2, out);
}

// Round 4
// 135.740 us; speedup vs baseline: 1.5307x; 1.0465x over previous
//
#include <hip/hip_runtime.h>
#include <hip/hip_bf16.h>
#include <stdint.h>

// ReplicatorDerivLayer on MI355X. Pipeline:
//  prep_x: x f32 -> xb bf16 [b][e][s] + xbT bf16 [b][s][e]
//  Wcat = [W1^T ; W2] bf16 [1024][512]
//  Fcat[s][0:512]=F1T, Fcat[s][512:1024]=F2T  (fused GEMM M=2048 N=1024 K=512)
//  Wm[s][t] = sum_f F1T[s][f] F2T[t][f], lower-tri tiles only (diag masked)
//  fit[e][s] = sum_t xb[e][t] Wm[s][t]  (chunked split-K, plain stores, no atomics)
//  out = relu(x * (1 + fit - avg)),  avg[e] = sum_s x*fit   (x from bf16 here)
//
// GEMM: 256x256 tile, BK=64, 8 waves, 4-phase/K-tile, counted vmcnt(4),
// XOR-swizzled LDS. This round: XCD-locality grids (fetch-bound fix).

#define SEQ 2048
#define EMB 512
#define NBATCH 8

typedef unsigned short u16;
typedef __bf16 bf16x8 __attribute__((ext_vector_type(8)));
typedef float f32x4 __attribute__((ext_vector_type(4)));
typedef u16 u16x8 __attribute__((ext_vector_type(8)));

#define AS1 __attribute__((address_space(1)))
#define AS3 __attribute__((address_space(3)))

#define SBAR do { __builtin_amdgcn_sched_barrier(0); __builtin_amdgcn_s_barrier(); \
                  __builtin_amdgcn_sched_barrier(0); } while (0)
#define LGKM0 do { asm volatile("s_waitcnt lgkmcnt(0)" ::: "memory"); \
                   __builtin_amdgcn_sched_barrier(0); } while (0)

__device__ __forceinline__ u16 f2bf(float f) {
  uint32_t u = __builtin_bit_cast(uint32_t, f);
  uint32_t r = u + 0x7FFFu + ((u >> 16) & 1u);
  return (u16)(r >> 16);
}
__device__ __forceinline__ float bf2f(u16 u) {
  return __builtin_bit_cast(float, (uint32_t)u << 16);
}

__device__ __forceinline__ void gld_lds16(const void* g, void* l) {
  __builtin_amdgcn_global_load_lds((AS1 uint32_t*)g, (AS3 uint32_t*)l, 16, 0, 0);
}

// ---------------- prep_x: xb [e][s] and xbT [s][e] in one pass ----------------
__global__ __launch_bounds__(256) void prep_x_kernel(const float* __restrict__ x,
    u16* __restrict__ xb, u16* __restrict__ xbT) {
  __shared__ float tile[64][65];
  const int b = blockIdx.z;
  const int s0 = blockIdx.x * 64, e0 = blockIdx.y * 64;
  const float* xin = x + (size_t)b * EMB * SEQ;
  const int tid = threadIdx.x;
  #pragma unroll
  for (int it = 0; it < 4; ++it) {
    int idx = it * 256 + tid;
    int r = idx >> 4, c4 = idx & 15;
    float4 v = *(const float4*)(xin + (size_t)(e0 + r) * SEQ + s0 + c4 * 4);
    tile[r][c4 * 4 + 0] = v.x; tile[r][c4 * 4 + 1] = v.y;
    tile[r][c4 * 4 + 2] = v.z; tile[r][c4 * 4 + 3] = v.w;
  }
  __syncthreads();
  u16* ob = xb + (size_t)b * EMB * SEQ;
  #pragma unroll
  for (int it = 0; it < 2; ++it) {
    int idx = it * 256 + tid; int r = idx >> 3, c8 = idx & 7;
    u16x8 o;
    #pragma unroll
    for (int q = 0; q < 8; ++q) o[q] = f2bf(tile[r][c8 * 8 + q]);
    *(u16x8*)(ob + (size_t)(e0 + r) * SEQ + s0 + c8 * 8) = o;
  }
  u16* obT = xbT + (size_t)b * SEQ * EMB;
  #pragma unroll
  for (int it = 0; it < 2; ++it) {
    int idx = it * 256 + tid; int r = idx >> 3, c8 = idx & 7;
    u16x8 o;
    #pragma unroll
    for (int q = 0; q < 8; ++q) o[q] = f2bf(tile[c8 * 8 + q][r]);
    *(u16x8*)(obT + (size_t)(s0 + r) * EMB + e0 + c8 * 8) = o;
  }
}

__global__ __launch_bounds__(256) void cast_bf16_kernel(const float* __restrict__ in,
                                                        u16* __restrict__ out, int n4) {
  int i = blockIdx.x * 256 + threadIdx.x;
  if (i >= n4) return;
  float4 v = reinterpret_cast<const float4*>(in)[i];
  ushort4 r;
  r.x = f2bf(v.x); r.y = f2bf(v.y); r.z = f2bf(v.z); r.w = f2bf(v.w);
  reinterpret_cast<ushort4*>(out)[i] = r;
}

__global__ __launch_bounds__(256) void transpose_cast_kernel(const float* __restrict__ in,
    u16* __restrict__ out, int R, int C) {
  __shared__ float tile[32][33];
  const int c0 = blockIdx.x * 32, r0 = blockIdx.y * 32;
  const int tx = threadIdx.x, ty = threadIdx.y;  // (32, 8)
  #pragma unroll
  for (int i = 0; i < 32; i += 8)
    tile[ty + i][tx] = in[(size_t)(r0 + ty + i) * C + c0 + tx];
  __syncthreads();
  #pragma unroll
  for (int i = 0; i < 32; i += 8)
    out[(size_t)(c0 + ty + i) * R + r0 + tx] = f2bf(tile[tx][ty + i]);
}

// ---------------- 256x256 4-phase bt-GEMM: C[m][n] = sum_k A[m][k] B[n][k] ----------------
// MODE 0: plain, bf16 out; grid (m, n) so same-A blocks share an XCD.
// MODE 1: lower-tri grid with XCD chunk-perm (36 = 8 chunks of 4/5 row-major
//         tri tiles; chunk c <-> blockIdx.x % 8 -> one XCD per chunk).
// MODE 2: chunked split-K (15 slots, k0-major order), f32 stores, grid (m, slot).
template<int MODE>
__global__ __launch_bounds__(512, 2) void gemm8_kernel(
    const u16* __restrict__ Ag, const u16* __restrict__ Bg, void* __restrict__ Cg,
    float* __restrict__ P1out, float* __restrict__ P2out,
    int ldA, int ldB, int ldC, long sA, long sB, long sC, int Kfull) {
  const int tid  = threadIdx.x;
  const int lane = tid & 63;
  const int wave = tid >> 6;
  const int wr = wave >> 2;       // 0..1  (M half)
  const int wc = wave & 3;        // 0..3  (N quarter)
  const int bz = blockIdx.z;

  int bm, bn, k0, kend, dest = 0;
  if (MODE == 0) {
    bm = blockIdx.x; bn = blockIdx.y; k0 = 0; kend = Kfull;
  } else if (MODE == 1) {
    // XCD-bijective chunk perm: chunk c = x%8 (sizes 5,5,5,5,4,4,4,4),
    // within-chunk ii = x>>3; tiles row-major over the lower triangle.
    int xx = blockIdx.x;
    int c = xx & 7, ii = xx >> 3;
    int tile = (c < 4) ? (c * 5 + ii) : (20 + (c - 4) * 4 + ii);
    int L = tile, i = 0;
    while (L >= i + 1) { L -= i + 1; ++i; }
    bm = i; bn = L; k0 = 0; kend = Kfull;
  } else {
    // slots k0-major so same-A-chunk (xb[.][k0..]) slots cluster on few XCDs
    static const int tj[15]  = {0,1,2,3,4,5,6,7, 3,4,5,6,7, 6,7};
    static const int tk0[15] = {0,0,0,0,0,0,0,0, 768,768,768,768,768, 1536,1536};
    static const int tk1[15] = {256,512,768,768,768,768,768,768, 1024,1280,1536,1536,1536, 1792,2048};
    static const int tds[15] = {0,0,0,0,0,0,0,0, 1,1,1,1,1, 2,2};
    const int L = blockIdx.y;
    bm = blockIdx.x; bn = tj[L]; k0 = tk0[L]; kend = tk1[L]; dest = tds[L];
  }
  const int nk = (kend - k0) >> 6;

  const u16* Ab = Ag + (size_t)bz * sA + (size_t)(bm * 256) * ldA;
  const u16* Bb = Bg + (size_t)bz * sB + (size_t)(bn * 256) * ldB;

  // 2 dbuf x (2 halves x 128 rows x 64 cols) per operand = 128 KiB
  __shared__ __align__(16) u16 LA[2][256 * 64];
  __shared__ __align__(16) u16 LB[2][256 * 64];

  auto stage_half = [&](const u16* gbase, int ldG, int rowOff, int kcol, u16* lds) {
    #pragma unroll
    for (int p = 0; p < 2; ++p) {
      int c = p * 512 + tid;              // chunk 0..1023
      int row = c >> 3, cc = c & 7;
      int cs = cc ^ (row & 7);
      gld_lds16(gbase + (size_t)(rowOff + row) * ldG + kcol + cs * 8,
                lds + (size_t)(p * 512 + wave * 64) * 8);
    }
  };

  auto ldfrag = [&](const u16* base, int rloc, int c2) -> bf16x8 {
    int cs = c2 ^ (rloc & 7);
    return *reinterpret_cast<const bf16x8*>(base + (size_t)(rloc * 8 + cs) * 8);
  };

  f32x4 acc[8][4];
  #pragma unroll
  for (int i = 0; i < 8; ++i)
    #pragma unroll
    for (int j = 0; j < 4; ++j) acc[i][j] = (f32x4){0.f, 0.f, 0.f, 0.f};

  // prologue stage order: 0.A0, 0.A1, 0.B0, 0.B1, [1.B0, 1.B1]
  stage_half(Ab, ldA, 0,   k0, LA[0]);
  stage_half(Ab, ldA, 128, k0, LA[0] + 8192);
  stage_half(Bb, ldB, 0,   k0, LB[0]);
  stage_half(Bb, ldB, 128, k0, LB[0] + 8192);
  if (nk > 1) {
    stage_half(Bb, ldB, 0,   k0 + 64, LB[1]);
    stage_half(Bb, ldB, 128, k0 + 64, LB[1] + 8192);
  }
  if (nk > 1) { asm volatile("s_waitcnt vmcnt(4)" ::: "memory"); }
  else        { asm volatile("s_waitcnt vmcnt(0)" ::: "memory"); }
  SBAR;

  const int ar = lane & 15;
  const int asel = lane >> 4;

  bf16x8 af[4][2], bf0[2][2], bf1[2][2];

  for (int t = 0; t < nk; ++t) {
    const int sel = t & 1;
    const u16* a_ = LA[sel];
    const u16* b_ = LB[sel];

    // ---- P1: read A[m0-3], B[n0-1]; stage (t+1).A-h0; MFMA mA x nA ----
    #pragma unroll
    for (int m = 0; m < 4; ++m)
      #pragma unroll
      for (int kk = 0; kk < 2; ++kk)
        af[m][kk] = ldfrag(a_, wr * 128 + m * 16 + ar, kk * 4 + asel);
    #pragma unroll
    for (int n = 0; n < 2; ++n)
      #pragma unroll
      for (int kk = 0; kk < 2; ++kk)
        bf0[n][kk] = ldfrag(b_, wc * 64 + n * 16 + ar, kk * 4 + asel);
    if (t + 1 < nk) stage_half(Ab, ldA, 0, k0 + (t + 1) * 64, LA[sel ^ 1]);
    SBAR; LGKM0;
    __builtin_amdgcn_s_setprio(1);
    #pragma unroll
    for (int m = 0; m < 4; ++m)
      #pragma unroll
      for (int n = 0; n < 2; ++n)
        #pragma unroll
        for (int kk = 0; kk < 2; ++kk)
          acc[m][n] = __builtin_amdgcn_mfma_f32_16x16x32_bf16(af[m][kk], bf0[n][kk], acc[m][n], 0, 0, 0);
    __builtin_amdgcn_s_setprio(0);
    SBAR;

    // ---- P2: read B[n2-3]; stage (t+1).A-h1; MFMA mA x nB ----
    #pragma unroll
    for (int n = 0; n < 2; ++n)
      #pragma unroll
      for (int kk = 0; kk < 2; ++kk)
        bf1[n][kk] = ldfrag(b_, wc * 64 + (n + 2) * 16 + ar, kk * 4 + asel);
    if (t + 1 < nk) stage_half(Ab, ldA, 128, k0 + (t + 1) * 64, LA[sel ^ 1] + 8192);
    SBAR; LGKM0;
    __builtin_amdgcn_s_setprio(1);
    #pragma unroll
    for (int m = 0; m < 4; ++m)
      #pragma unroll
      for (int n = 0; n < 2; ++n)
        #pragma unroll
        for (int kk = 0; kk < 2; ++kk)
          acc[m][n + 2] = __builtin_amdgcn_mfma_f32_16x16x32_bf16(af[m][kk], bf1[n][kk], acc[m][n + 2], 0, 0, 0);
    __builtin_amdgcn_s_setprio(0);
    SBAR;

    // ---- P3: read A[m4-7]; stage (t+2).B-h0; MFMA mB x nB ----
    #pragma unroll
    for (int m = 0; m < 4; ++m)
      #pragma unroll
      for (int kk = 0; kk < 2; ++kk)
        af[m][kk] = ldfrag(a_, wr * 128 + 64 + m * 16 + ar, kk * 4 + asel);
    if (t + 2 < nk) stage_half(Bb, ldB, 0, k0 + (t + 2) * 64, LB[sel]);
    SBAR; LGKM0;
    __builtin_amdgcn_s_setprio(1);
    #pragma unroll
    for (int m = 0; m < 4; ++m)
      #pragma unroll
      for (int n = 0; n < 2; ++n)
        #pragma unroll
        for (int kk = 0; kk < 2; ++kk)
          acc[m + 4][n + 2] = __builtin_amdgcn_mfma_f32_16x16x32_bf16(af[m][kk], bf1[n][kk], acc[m + 4][n + 2], 0, 0, 0);
    __builtin_amdgcn_s_setprio(0);
    SBAR;

    // ---- P4: stage (t+2).B-h1; MFMA mB x nA; counted vmcnt for next tile ----
    if (t + 2 < nk) stage_half(Bb, ldB, 128, k0 + (t + 2) * 64, LB[sel] + 8192);
    SBAR;
    __builtin_amdgcn_s_setprio(1);
    #pragma unroll
    for (int m = 0; m < 4; ++m)
      #pragma unroll
      for (int n = 0; n < 2; ++n)
        #pragma unroll
        for (int kk = 0; kk < 2; ++kk)
          acc[m + 4][n] = __builtin_amdgcn_mfma_f32_16x16x32_bf16(af[m][kk], bf0[n][kk], acc[m + 4][n], 0, 0, 0);
    __builtin_amdgcn_s_setprio(0);
    if (t + 1 < nk) {
      if (t + 2 < nk) { asm volatile("s_waitcnt vmcnt(4)" ::: "memory"); }
      else            { asm volatile("s_waitcnt vmcnt(0)" ::: "memory"); }
    }
    SBAR;
  }

  // epilogue: D mapping col = lane&15, row = (lane>>4)*4 + r
  const int r0 = (lane >> 4) * 4;
  const int cn = lane & 15;
  #pragma unroll
  for (int m = 0; m < 8; ++m) {
    #pragma unroll
    for (int n = 0; n < 4; ++n) {
      const int gcol = bn * 256 + wc * 64 + n * 16 + cn;
      #pragma unroll
      for (int r = 0; r < 4; ++r) {
        const int grow = bm * 256 + wr * 128 + m * 16 + r0 + r;
        float v = acc[m][n][r];
        if (MODE == 2) {
          float* base; int ldc, coff;
          if (dest == 0)      { base = (float*)Cg + (size_t)bz * sC; ldc = SEQ;  coff = 0; }
          else if (dest == 1) { base = P1out + (size_t)bz * (512 * 1280); ldc = 1280; coff = 768; }
          else                { base = P2out + (size_t)bz * (512 * 512);  ldc = 512;  coff = 1536; }
          base[(size_t)grow * ldc + (gcol - coff)] = v;
        } else {
          if (MODE == 1 && bm == bn && gcol > grow) v = 0.f;
          ((u16*)Cg)[(size_t)bz * sC + (size_t)grow * ldC + gcol] = f2bf(v);
        }
      }
    }
  }
}

// ---------------- finalize: fit = fit + partials; avg-reduce; relu ----------------
// x read from bf16 (xb) to cut 48 MB of HBM traffic.
__global__ __launch_bounds__(256) void finalize_kernel(const u16* __restrict__ xb,
    const float* __restrict__ fit, const float* __restrict__ fitP,
    const float* __restrict__ fitP2, float* __restrict__ out) {
  const size_t row = blockIdx.x;  // b*EMB + e
  const u16* xr = xb + row * SEQ;
  const float* fr = fit + row * SEQ;
  const float* p1 = fitP + row * 1280;   // s in [768, 2048)
  const float* p2 = fitP2 + row * 512;   // s in [1536, 2048)
  float* orow = out + row * SEQ;
  const int tid = threadIdx.x;

  float xv[2][4]; float4 fv[2];
  float part = 0.f;
  #pragma unroll
  for (int i = 0; i < 2; ++i) {
    const int s0 = i * 1024 + tid * 4;
    ushort4 xu = *reinterpret_cast<const ushort4*>(xr + s0);
    xv[i][0] = bf2f(xu.x); xv[i][1] = bf2f(xu.y); xv[i][2] = bf2f(xu.z); xv[i][3] = bf2f(xu.w);
    fv[i] = reinterpret_cast<const float4*>(fr)[i * 256 + tid];
    if (s0 >= 768) {
      float4 a = *reinterpret_cast<const float4*>(p1 + (s0 - 768));
      fv[i].x += a.x; fv[i].y += a.y; fv[i].z += a.z; fv[i].w += a.w;
    }
    if (s0 >= 1536) {
      float4 a = *reinterpret_cast<const float4*>(p2 + (s0 - 1536));
      fv[i].x += a.x; fv[i].y += a.y; fv[i].z += a.z; fv[i].w += a.w;
    }
    part += xv[i][0] * fv[i].x + xv[i][1] * fv[i].y + xv[i][2] * fv[i].z + xv[i][3] * fv[i].w;
  }
  #pragma unroll
  for (int off = 1; off < 64; off <<= 1) part += __shfl_xor(part, off);
  __shared__ float wsum[4];
  const int wave = tid >> 6, lane = tid & 63;
  if (lane == 0) wsum[wave] = part;
  __syncthreads();
  const float avg = wsum[0] + wsum[1] + wsum[2] + wsum[3];

  #pragma unroll
  for (int i = 0; i < 2; ++i) {
    float4 o;
    o.x = xv[i][0] * (1.f + fv[i].x - avg); o.x = o.x > 0.f ? o.x : 0.f;
    o.y = xv[i][1] * (1.f + fv[i].y - avg); o.y = o.y > 0.f ? o.y : 0.f;
    o.z = xv[i][2] * (1.f + fv[i].z - avg); o.z = o.z > 0.f ? o.z : 0.f;
    o.w = xv[i][3] * (1.f + fv[i].w - avg); o.w = o.w > 0.f ? o.w : 0.f;
    reinterpret_cast<float4*>(orow)[i * 256 + tid] = o;
  }
}

extern "C" void kernel_launch(void* const* d_in, const int* in_sizes, int n_in,
                              void* d_out, int out_size, void* d_ws, size_t ws_size,
                              hipStream_t stream) {
  const float* x  = (const float*)d_in[0];
  const float* W1 = (const float*)d_in[1];
  const float* W2 = (const float*)d_in[2];
  float* out = (float*)d_out;

  char* ws = (char*)d_ws;
  const size_t nX = (size_t)NBATCH * EMB * SEQ;  // 8,388,608

  size_t off = 0;
  u16* xb   = (u16*)(ws + off); off += nX * 2;                          // 16 MB
  const size_t offFit = off;                                            // fit aliases xbT+Wcat+Fcat
  u16* xbT  = (u16*)(ws + off); off += nX * 2;                          // 16 MB (dead after projcat)
  u16* Wcat = (u16*)(ws + off); off += (size_t)1024 * 512 * 2;          // 1 MB  (dead after projcat)
  u16* Fcat = (u16*)(ws + off); off += (size_t)NBATCH * SEQ * 1024 * 2; // 32 MB (dead after Gram)
  u16* Wm   = (u16*)(ws + off); off += (size_t)NBATCH * SEQ * SEQ * 2;  // 64 MB
  float* fitP  = (float*)(ws + off); off += (size_t)NBATCH * 512 * 1280 * 4; // 21 MB
  float* fitP2 = (float*)(ws + off); off += (size_t)NBATCH * 512 * 512 * 4;  // 8.4 MB
  float* fit = (float*)(ws + offFit);                                   // 33.5 MB
  // total: ~157 MiB

  // 1) prep
  prep_x_kernel<<<dim3(SEQ / 64, EMB / 64, NBATCH), 256, 0, stream>>>(x, xb, xbT);
  transpose_cast_kernel<<<dim3(EMB / 32, EMB / 32), dim3(32, 8), 0, stream>>>(W1, Wcat, EMB, EMB);
  cast_bf16_kernel<<<EMB * EMB / 4 / 256, 256, 0, stream>>>(W2, Wcat + (size_t)512 * 512, EMB * EMB / 4);

  // 2) fused projections: Fcat[s][n] = sum_k xbT[s][k] * Wcat[n][k]
  //    grid (m,n): same-A (same m) blocks are linear-id = m (mod 8) -> same XCD
  gemm8_kernel<0><<<dim3(8, 4, NBATCH), 512, 0, stream>>>(
      xbT, Wcat, Fcat, nullptr, nullptr, EMB, EMB, 1024, (long)SEQ * EMB, 0, (long)SEQ * 1024, EMB);

  // 3) Gram lower-tri: Wm[s][t] = sum_f F1T[s][f] F2T[t][f]  (XCD chunk-perm inside)
  gemm8_kernel<1><<<dim3(36, 1, NBATCH), 512, 0, stream>>>(
      Fcat, Fcat + 512, Wm, nullptr, nullptr, 1024, 1024, SEQ,
      (long)SEQ * 1024, (long)SEQ * 1024, (long)SEQ * SEQ, EMB);

  // 4) fitness: fit[e][s] = sum_t xb[e][t] Wm[s][t]  (chunked split-K, grid (m, slot))
  gemm8_kernel<2><<<dim3(2, 15, NBATCH), 512, 0, stream>>>(
      xb, Wm, fit, fitP, fitP2, SEQ, SEQ, SEQ,
      (long)EMB * SEQ, (long)SEQ * SEQ, (long)EMB * SEQ, SEQ);

  // 5) finalize (sums fit + fitP + fitP2, computes avg, relu; x from bf16)
  finalize_kernel<<<NBATCH * EMB, 256, 0, stream>>>(xb, fit, fitP, fitP2, out);
}

// Round 5
// 133.674 us; speedup vs baseline: 1.5544x; 1.0155x over previous
//
#include <hip/hip_runtime.h>
#include <hip/hip_bf16.h>
#include <stdint.h>

// ReplicatorDerivLayer on MI355X — factorized (no 2048x2048 Wm).
//  prep_x: x f32 -> xb bf16 [b][e][s] + xbT bf16 [b][s][e]
//  Wcat = [W1^T ; W2] bf16 [1024][512]
//  projcat: Fcat[s][0:512]=F1T[s,f], Fcat[s][512:1024]=F2T[s,f]
//  aux:  F2n[f][t] = fitnesses2 in natural layout (M=512,N=2048,K=512)
//        Sd[b][i]  = masked diag Gram block (256x256, K=512), i=0..7
//  Gc[b][j][e,f] = sum_{t in blk j} xb[e,t] * F2n[f,t]   (K=256)
//  prefix: Gp[b][i-1] = sum_{j<i} Gc[b][j]  (bf16)
//  fitfused (per b, i, e-half): fit[e, blk i] = Gp_i . F1T^T  (K=512, skip i=0)
//                                            +  xb_blk . Sd^T (K=256)
//  finalize: avg = sum_s x*fit; out = relu(x*(1+fit-avg))
//
// All GEMMs: one 256x256 8-wave 4-phase pipelined engine (gemm_pipe),
// XOR-swizzled LDS, counted vmcnt(4), raw s_barrier.

#define SEQ 2048
#define EMB 512
#define NBATCH 8

typedef unsigned short u16;
typedef __bf16 bf16x8 __attribute__((ext_vector_type(8)));
typedef float f32x4 __attribute__((ext_vector_type(4)));
typedef u16 u16x8 __attribute__((ext_vector_type(8)));

#define AS1 __attribute__((address_space(1)))
#define AS3 __attribute__((address_space(3)))

#define SBAR do { __builtin_amdgcn_sched_barrier(0); __builtin_amdgcn_s_barrier(); \
                  __builtin_amdgcn_sched_barrier(0); } while (0)
#define LGKM0 do { asm volatile("s_waitcnt lgkmcnt(0)" ::: "memory"); \
                   __builtin_amdgcn_sched_barrier(0); } while (0)

__device__ __forceinline__ u16 f2bf(float f) {
  uint32_t u = __builtin_bit_cast(uint32_t, f);
  uint32_t r = u + 0x7FFFu + ((u >> 16) & 1u);
  return (u16)(r >> 16);
}
__device__ __forceinline__ float bf2f(u16 u) {
  return __builtin_bit_cast(float, (uint32_t)u << 16);
}
__device__ __forceinline__ void gld_lds16(const void* g, void* l) {
  __builtin_amdgcn_global_load_lds((AS1 uint32_t*)g, (AS3 uint32_t*)l, 16, 0, 0);
}

// ---------------- prep_x ----------------
__global__ __launch_bounds__(256) void prep_x_kernel(const float* __restrict__ x,
    u16* __restrict__ xb, u16* __restrict__ xbT) {
  __shared__ float tile[64][65];
  const int b = blockIdx.z;
  const int s0 = blockIdx.x * 64, e0 = blockIdx.y * 64;
  const float* xin = x + (size_t)b * EMB * SEQ;
  const int tid = threadIdx.x;
  #pragma unroll
  for (int it = 0; it < 4; ++it) {
    int idx = it * 256 + tid;
    int r = idx >> 4, c4 = idx & 15;
    float4 v = *(const float4*)(xin + (size_t)(e0 + r) * SEQ + s0 + c4 * 4);
    tile[r][c4 * 4 + 0] = v.x; tile[r][c4 * 4 + 1] = v.y;
    tile[r][c4 * 4 + 2] = v.z; tile[r][c4 * 4 + 3] = v.w;
  }
  __syncthreads();
  u16* ob = xb + (size_t)b * EMB * SEQ;
  #pragma unroll
  for (int it = 0; it < 2; ++it) {
    int idx = it * 256 + tid; int r = idx >> 3, c8 = idx & 7;
    u16x8 o;
    #pragma unroll
    for (int q = 0; q < 8; ++q) o[q] = f2bf(tile[r][c8 * 8 + q]);
    *(u16x8*)(ob + (size_t)(e0 + r) * SEQ + s0 + c8 * 8) = o;
  }
  u16* obT = xbT + (size_t)b * SEQ * EMB;
  #pragma unroll
  for (int it = 0; it < 2; ++it) {
    int idx = it * 256 + tid; int r = idx >> 3, c8 = idx & 7;
    u16x8 o;
    #pragma unroll
    for (int q = 0; q < 8; ++q) o[q] = f2bf(tile[c8 * 8 + q][r]);
    *(u16x8*)(obT + (size_t)(s0 + r) * EMB + e0 + c8 * 8) = o;
  }
}

__global__ __launch_bounds__(256) void cast_bf16_kernel(const float* __restrict__ in,
                                                        u16* __restrict__ out, int n4) {
  int i = blockIdx.x * 256 + threadIdx.x;
  if (i >= n4) return;
  float4 v = reinterpret_cast<const float4*>(in)[i];
  ushort4 r;
  r.x = f2bf(v.x); r.y = f2bf(v.y); r.z = f2bf(v.z); r.w = f2bf(v.w);
  reinterpret_cast<ushort4*>(out)[i] = r;
}

__global__ __launch_bounds__(256) void transpose_cast_kernel(const float* __restrict__ in,
    u16* __restrict__ out, int R, int C) {
  __shared__ float tile[32][33];
  const int c0 = blockIdx.x * 32, r0 = blockIdx.y * 32;
  const int tx = threadIdx.x, ty = threadIdx.y;  // (32, 8)
  #pragma unroll
  for (int i = 0; i < 32; i += 8)
    tile[ty + i][tx] = in[(size_t)(r0 + ty + i) * C + c0 + tx];
  __syncthreads();
  #pragma unroll
  for (int i = 0; i < 32; i += 8)
    out[(size_t)(c0 + ty + i) * R + r0 + tx] = f2bf(tile[tx][ty + i]);
}

// ---------------- the 256x256 4-phase pipelined engine ----------------
struct Smem {
  __align__(16) u16 LA[2][256 * 64];
  __align__(16) u16 LB[2][256 * 64];
};

__device__ __forceinline__ void gemm_pipe(const u16* __restrict__ Ab, int ldA,
    const u16* __restrict__ Bb, int ldB, int nk, Smem& sm, f32x4 (&acc)[8][4]) {
  const int tid  = threadIdx.x;
  const int lane = tid & 63;
  const int wave = tid >> 6;
  const int wr = wave >> 2;
  const int wc = wave & 3;

  auto stage_half = [&](const u16* gbase, int ldG, int rowOff, int kcol, u16* lds) {
    #pragma unroll
    for (int p = 0; p < 2; ++p) {
      int c = p * 512 + tid;              // chunk 0..1023
      int row = c >> 3, cc = c & 7;
      int cs = cc ^ (row & 7);
      gld_lds16(gbase + (size_t)(rowOff + row) * ldG + kcol + cs * 8,
                lds + (size_t)(p * 512 + wave * 64) * 8);
    }
  };
  auto ldfrag = [&](const u16* base, int rloc, int c2) -> bf16x8 {
    int cs = c2 ^ (rloc & 7);
    return *reinterpret_cast<const bf16x8*>(base + (size_t)(rloc * 8 + cs) * 8);
  };

  // prologue stage order: 0.A0, 0.A1, 0.B0, 0.B1, [1.B0, 1.B1]
  stage_half(Ab, ldA, 0,   0, sm.LA[0]);
  stage_half(Ab, ldA, 128, 0, sm.LA[0] + 8192);
  stage_half(Bb, ldB, 0,   0, sm.LB[0]);
  stage_half(Bb, ldB, 128, 0, sm.LB[0] + 8192);
  if (nk > 1) {
    stage_half(Bb, ldB, 0,   64, sm.LB[1]);
    stage_half(Bb, ldB, 128, 64, sm.LB[1] + 8192);
  }
  if (nk > 1) { asm volatile("s_waitcnt vmcnt(4)" ::: "memory"); }
  else        { asm volatile("s_waitcnt vmcnt(0)" ::: "memory"); }
  SBAR;

  const int ar = lane & 15;
  const int asel = lane >> 4;
  bf16x8 af[4][2], bf0[2][2], bf1[2][2];

  for (int t = 0; t < nk; ++t) {
    const int sel = t & 1;
    const u16* a_ = sm.LA[sel];
    const u16* b_ = sm.LB[sel];

    // P1: read A[m0-3], B[n0-1]; stage (t+1).A-h0; MFMA mA x nA
    #pragma unroll
    for (int m = 0; m < 4; ++m)
      #pragma unroll
      for (int kk = 0; kk < 2; ++kk)
        af[m][kk] = ldfrag(a_, wr * 128 + m * 16 + ar, kk * 4 + asel);
    #pragma unroll
    for (int n = 0; n < 2; ++n)
      #pragma unroll
      for (int kk = 0; kk < 2; ++kk)
        bf0[n][kk] = ldfrag(b_, wc * 64 + n * 16 + ar, kk * 4 + asel);
    if (t + 1 < nk) stage_half(Ab, ldA, 0, (t + 1) * 64, sm.LA[sel ^ 1]);
    SBAR; LGKM0;
    __builtin_amdgcn_s_setprio(1);
    #pragma unroll
    for (int m = 0; m < 4; ++m)
      #pragma unroll
      for (int n = 0; n < 2; ++n)
        #pragma unroll
        for (int kk = 0; kk < 2; ++kk)
          acc[m][n] = __builtin_amdgcn_mfma_f32_16x16x32_bf16(af[m][kk], bf0[n][kk], acc[m][n], 0, 0, 0);
    __builtin_amdgcn_s_setprio(0);
    SBAR;

    // P2: read B[n2-3]; stage (t+1).A-h1; MFMA mA x nB
    #pragma unroll
    for (int n = 0; n < 2; ++n)
      #pragma unroll
      for (int kk = 0; kk < 2; ++kk)
        bf1[n][kk] = ldfrag(b_, wc * 64 + (n + 2) * 16 + ar, kk * 4 + asel);
    if (t + 1 < nk) stage_half(Ab, ldA, 128, (t + 1) * 64, sm.LA[sel ^ 1] + 8192);
    SBAR; LGKM0;
    __builtin_amdgcn_s_setprio(1);
    #pragma unroll
    for (int m = 0; m < 4; ++m)
      #pragma unroll
      for (int n = 0; n < 2; ++n)
        #pragma unroll
        for (int kk = 0; kk < 2; ++kk)
          acc[m][n + 2] = __builtin_amdgcn_mfma_f32_16x16x32_bf16(af[m][kk], bf1[n][kk], acc[m][n + 2], 0, 0, 0);
    __builtin_amdgcn_s_setprio(0);
    SBAR;

    // P3: read A[m4-7]; stage (t+2).B-h0; MFMA mB x nB
    #pragma unroll
    for (int m = 0; m < 4; ++m)
      #pragma unroll
      for (int kk = 0; kk < 2; ++kk)
        af[m][kk] = ldfrag(a_, wr * 128 + 64 + m * 16 + ar, kk * 4 + asel);
    if (t + 2 < nk) stage_half(Bb, ldB, 0, (t + 2) * 64, sm.LB[sel]);
    SBAR; LGKM0;
    __builtin_amdgcn_s_setprio(1);
    #pragma unroll
    for (int m = 0; m < 4; ++m)
      #pragma unroll
      for (int n = 0; n < 2; ++n)
        #pragma unroll
        for (int kk = 0; kk < 2; ++kk)
          acc[m + 4][n + 2] = __builtin_amdgcn_mfma_f32_16x16x32_bf16(af[m][kk], bf1[n][kk], acc[m + 4][n + 2], 0, 0, 0);
    __builtin_amdgcn_s_setprio(0);
    SBAR;

    // P4: stage (t+2).B-h1; MFMA mB x nA; counted vmcnt for next tile
    if (t + 2 < nk) stage_half(Bb, ldB, 128, (t + 2) * 64, sm.LB[sel] + 8192);
    SBAR;
    __builtin_amdgcn_s_setprio(1);
    #pragma unroll
    for (int m = 0; m < 4; ++m)
      #pragma unroll
      for (int n = 0; n < 2; ++n)
        #pragma unroll
        for (int kk = 0; kk < 2; ++kk)
          acc[m + 4][n] = __builtin_amdgcn_mfma_f32_16x16x32_bf16(af[m][kk], bf0[n][kk], acc[m + 4][n], 0, 0, 0);
    __builtin_amdgcn_s_setprio(0);
    if (t + 1 < nk) {
      if (t + 2 < nk) { asm volatile("s_waitcnt vmcnt(4)" ::: "memory"); }
      else            { asm volatile("s_waitcnt vmcnt(0)" ::: "memory"); }
    }
    SBAR;
  }
}

// ---------------- GEMM kernels (one template, 4 modes) ----------------
// MODE 0 projcat: grid (8,4,8):  Fcat = xbT . Wcat^T          (bf16 out)
// MODE 1 aux:     grid (24,1,8): x<16 -> F2n = W2b . xbT^T; x>=16 -> Sd[i] masked diag
// MODE 2 gc:      grid (4,1,64): Gc[b][j] = xb_blkj . F2n_blkj^T (bf16 out)
// MODE 3 fit:     grid (16,1,8): fit[e,blk i] = Gp_i.F1T^T + xb_blk.Sd^T (f32 out)
template<int MODE>
__global__ __launch_bounds__(512, 2) void k_gemm(
    const u16* __restrict__ X1, const u16* __restrict__ X2,
    const u16* __restrict__ X3, const u16* __restrict__ X4,
    u16* __restrict__ O16, u16* __restrict__ O16b, float* __restrict__ O32) {
  __shared__ Smem sm;
  const int tid  = threadIdx.x;
  const int lane = tid & 63;
  const int wave = tid >> 6;
  const int wr = wave >> 2;
  const int wc = wave & 3;
  const int bz = blockIdx.z;

  f32x4 acc[8][4];
  #pragma unroll
  for (int i = 0; i < 8; ++i)
    #pragma unroll
    for (int j = 0; j < 4; ++j) acc[i][j] = (f32x4){0.f, 0.f, 0.f, 0.f};

  const int r0 = (lane >> 4) * 4;
  const int cn = lane & 15;

  if (MODE == 0) {
    // A = xbT[b] rows bm*256, ld 512; B = Wcat rows bn*256, ld 512; nk=8
    const int bm = blockIdx.x, bn = blockIdx.y;
    const u16* A = X1 + (size_t)bz * SEQ * EMB + (size_t)(bm * 256) * 512;
    const u16* B = X2 + (size_t)(bn * 256) * 512;
    gemm_pipe(A, 512, B, 512, 8, sm, acc);
    u16* C = O16 + (size_t)bz * SEQ * 1024;
    #pragma unroll
    for (int m = 0; m < 8; ++m)
      #pragma unroll
      for (int n = 0; n < 4; ++n)
        #pragma unroll
        for (int r = 0; r < 4; ++r) {
          int lr = wr * 128 + m * 16 + r0 + r, lc = wc * 64 + n * 16 + cn;
          C[(size_t)(bm * 256 + lr) * 1024 + bn * 256 + lc] = f2bf(acc[m][n][r]);
        }
  } else if (MODE == 1) {
    const int xx = blockIdx.x;
    if (xx < 16) {
      // F2n[f][t]: A = W2b = X1, ld 512; B = xbT[b], ld 512
      const int m2 = xx >> 3, n2 = xx & 7;
      const u16* A = X1 + (size_t)(m2 * 256) * 512;
      const u16* B = X2 + (size_t)bz * SEQ * EMB + (size_t)(n2 * 256) * 512;
      gemm_pipe(A, 512, B, 512, 8, sm, acc);
      u16* C = O16 + (size_t)bz * EMB * SEQ;
      #pragma unroll
      for (int m = 0; m < 8; ++m)
        #pragma unroll
        for (int n = 0; n < 4; ++n)
          #pragma unroll
          for (int r = 0; r < 4; ++r) {
            int lr = wr * 128 + m * 16 + r0 + r, lc = wc * 64 + n * 16 + cn;
            C[(size_t)(m2 * 256 + lr) * SEQ + n2 * 256 + lc] = f2bf(acc[m][n][r]);
          }
    } else {
      // Sd[b][i] = masked diag Gram: A = F1T rows i*256 (ld 1024), B = F2T rows i*256
      const int i = xx - 16;
      const u16* Fb = X3 + (size_t)bz * SEQ * 1024;
      const u16* A = Fb + (size_t)(i * 256) * 1024;
      const u16* B = Fb + 512 + (size_t)(i * 256) * 1024;
      gemm_pipe(A, 1024, B, 1024, 8, sm, acc);
      u16* C = O16b + (size_t)(bz * 8 + i) * 256 * 256;
      #pragma unroll
      for (int m = 0; m < 8; ++m)
        #pragma unroll
        for (int n = 0; n < 4; ++n)
          #pragma unroll
          for (int r = 0; r < 4; ++r) {
            int lr = wr * 128 + m * 16 + r0 + r, lc = wc * 64 + n * 16 + cn;
            float v = (lc > lr) ? 0.f : acc[m][n][r];  // keep t <= s
            C[(size_t)lr * 256 + lc] = f2bf(v);
          }
    }
  } else if (MODE == 2) {
    // Gc[b][j][e,f]: A = xb[b] + j*256 cols (ld 2048), B = F2n[b] + j*256 cols (ld 2048); nk=4
    const int m = blockIdx.x >> 1, n = blockIdx.x & 1;
    const int b = bz >> 3, j = bz & 7;
    const u16* A = X1 + (size_t)b * EMB * SEQ + (size_t)(m * 256) * SEQ + j * 256;
    const u16* B = X2 + (size_t)b * EMB * SEQ + (size_t)(n * 256) * SEQ + j * 256;
    gemm_pipe(A, SEQ, B, SEQ, 4, sm, acc);
    u16* C = O16 + (size_t)(b * 8 + j) * EMB * EMB;
    #pragma unroll
    for (int mm = 0; mm < 8; ++mm)
      #pragma unroll
      for (int nn = 0; nn < 4; ++nn)
        #pragma unroll
        for (int r = 0; r < 4; ++r) {
          int lr = wr * 128 + mm * 16 + r0 + r, lc = wc * 64 + nn * 16 + cn;
          C[(size_t)(m * 256 + lr) * EMB + n * 256 + lc] = f2bf(acc[mm][nn][r]);
        }
  } else {
    // fitfused: x = (m e-half, i s-block); seg1 (i>0): A=Gp[b][i-1]+m*256 rows (ld 512),
    // B=F1T rows i*256 (ld 1024), nk=8. seg2: A=xb[b]+m*256 rows, cols i*256 (ld 2048),
    // B=Sd[b][i] (ld 256), nk=4. Out f32 fit[b] rows m*256.., cols i*256..
    const int m = blockIdx.x & 1, i = blockIdx.x >> 1;
    if (i > 0) {
      const u16* A = X1 + (size_t)(bz * 7 + i - 1) * EMB * EMB + (size_t)(m * 256) * 512;
      const u16* B = X2 + (size_t)bz * SEQ * 1024 + (size_t)(i * 256) * 1024;
      gemm_pipe(A, 512, B, 1024, 8, sm, acc);
    }
    {
      const u16* A = X3 + (size_t)bz * EMB * SEQ + (size_t)(m * 256) * SEQ + i * 256;
      const u16* B = X4 + (size_t)(bz * 8 + i) * 256 * 256;
      gemm_pipe(A, SEQ, B, 256, 4, sm, acc);
    }
    float* C = O32 + (size_t)bz * EMB * SEQ;
    #pragma unroll
    for (int mm = 0; mm < 8; ++mm)
      #pragma unroll
      for (int nn = 0; nn < 4; ++nn)
        #pragma unroll
        for (int r = 0; r < 4; ++r) {
          int lr = wr * 128 + mm * 16 + r0 + r, lc = wc * 64 + nn * 16 + cn;
          C[(size_t)(m * 256 + lr) * SEQ + i * 256 + lc] = acc[mm][nn][r];
        }
  }
}

// ---------------- prefix over chunks: Gp[b][i-1] = sum_{j<i} Gc[b][j] ----------------
__global__ __launch_bounds__(256) void k_prefix(const u16* __restrict__ Gc,
                                                u16* __restrict__ Gp) {
  const int b = blockIdx.z;
  const size_t base = ((size_t)blockIdx.x * 256 + threadIdx.x) * 8;
  float run[8] = {0.f, 0.f, 0.f, 0.f, 0.f, 0.f, 0.f, 0.f};
  #pragma unroll
  for (int j = 0; j < 7; ++j) {
    u16x8 v = *(const u16x8*)(Gc + (size_t)(b * 8 + j) * EMB * EMB + base);
    u16x8 o;
    #pragma unroll
    for (int q = 0; q < 8; ++q) { run[q] += bf2f(v[q]); o[q] = f2bf(run[q]); }
    *(u16x8*)(Gp + (size_t)(b * 7 + j) * EMB * EMB + base) = o;
  }
}

// ---------------- finalize ----------------
__global__ __launch_bounds__(256) void finalize_kernel(const u16* __restrict__ xb,
    const float* __restrict__ fit, float* __restrict__ out) {
  const size_t row = blockIdx.x;  // b*EMB + e
  const u16* xr = xb + row * SEQ;
  const float* fr = fit + row * SEQ;
  float* orow = out + row * SEQ;
  const int tid = threadIdx.x;

  float xv[2][4]; float4 fv[2];
  float part = 0.f;
  #pragma unroll
  for (int i = 0; i < 2; ++i) {
    const int s0 = i * 1024 + tid * 4;
    ushort4 xu = *reinterpret_cast<const ushort4*>(xr + s0);
    xv[i][0] = bf2f(xu.x); xv[i][1] = bf2f(xu.y); xv[i][2] = bf2f(xu.z); xv[i][3] = bf2f(xu.w);
    fv[i] = reinterpret_cast<const float4*>(fr)[i * 256 + tid];
    part += xv[i][0] * fv[i].x + xv[i][1] * fv[i].y + xv[i][2] * fv[i].z + xv[i][3] * fv[i].w;
  }
  #pragma unroll
  for (int off = 1; off < 64; off <<= 1) part += __shfl_xor(part, off);
  __shared__ float wsum[4];
  const int wave = tid >> 6, lane = tid & 63;
  if (lane == 0) wsum[wave] = part;
  __syncthreads();
  const float avg = wsum[0] + wsum[1] + wsum[2] + wsum[3];

  #pragma unroll
  for (int i = 0; i < 2; ++i) {
    float4 o;
    o.x = xv[i][0] * (1.f + fv[i].x - avg); o.x = o.x > 0.f ? o.x : 0.f;
    o.y = xv[i][1] * (1.f + fv[i].y - avg); o.y = o.y > 0.f ? o.y : 0.f;
    o.z = xv[i][2] * (1.f + fv[i].z - avg); o.z = o.z > 0.f ? o.z : 0.f;
    o.w = xv[i][3] * (1.f + fv[i].w - avg); o.w = o.w > 0.f ? o.w : 0.f;
    reinterpret_cast<float4*>(orow)[i * 256 + tid] = o;
  }
}

extern "C" void kernel_launch(void* const* d_in, const int* in_sizes, int n_in,
                              void* d_out, int out_size, void* d_ws, size_t ws_size,
                              hipStream_t stream) {
  const float* x  = (const float*)d_in[0];
  const float* W1 = (const float*)d_in[1];
  const float* W2 = (const float*)d_in[2];
  float* out = (float*)d_out;

  char* ws = (char*)d_ws;
  const size_t nX = (size_t)NBATCH * EMB * SEQ;  // 8,388,608

  size_t off = 0;
  u16* xb   = (u16*)(ws + off); off += nX * 2;                          // 16 MB
  u16* Fcat = (u16*)(ws + off); off += (size_t)NBATCH * SEQ * 1024 * 2; // 32 MB
  const size_t offOverlay = off;                                        // fit overlays next 33 MB
  u16* xbT  = (u16*)(ws + off); off += nX * 2;                          // 16 MB (dead after aux)
  u16* Wcat = (u16*)(ws + off); off += (size_t)1024 * 512 * 2;          // 1 MB  (dead after aux)
  u16* F2n  = (u16*)(ws + off); off += nX * 2;                          // 16 MB (dead after Gc)
  u16* Sd   = (u16*)(ws + off); off += (size_t)NBATCH * 8 * 256 * 256 * 2;  // 8 MB
  u16* Gc   = (u16*)(ws + off); off += (size_t)NBATCH * 8 * EMB * EMB * 2;  // 32 MB
  u16* Gp   = (u16*)(ws + off); off += (size_t)NBATCH * 7 * EMB * EMB * 2;  // 28 MB
  float* fit = (float*)(ws + offOverlay);                               // 32 MB
  // total: ~149 MiB

  // 1) prep
  prep_x_kernel<<<dim3(SEQ / 64, EMB / 64, NBATCH), 256, 0, stream>>>(x, xb, xbT);
  transpose_cast_kernel<<<dim3(EMB / 32, EMB / 32), dim3(32, 8), 0, stream>>>(W1, Wcat, EMB, EMB);
  cast_bf16_kernel<<<EMB * EMB / 4 / 256, 256, 0, stream>>>(W2, Wcat + (size_t)512 * 512, EMB * EMB / 4);

  // 2) projcat: Fcat[s][n] = sum_k xbT[s][k] Wcat[n][k]
  k_gemm<0><<<dim3(8, 4, NBATCH), 512, 0, stream>>>(
      xbT, Wcat, nullptr, nullptr, Fcat, nullptr, nullptr);

  // 3) aux: F2n (natural-layout 2nd projection) + Sd (masked diag Gram blocks)
  k_gemm<1><<<dim3(24, 1, NBATCH), 512, 0, stream>>>(
      Wcat + (size_t)512 * 512, xbT, Fcat, nullptr, F2n, Sd, nullptr);

  // 4) Gc[b][j] = xb_blkj . F2n_blkj^T  (K=256 per chunk)
  k_gemm<2><<<dim3(4, 1, 64), 512, 0, stream>>>(
      xb, F2n, nullptr, nullptr, Gc, nullptr, nullptr);

  // 5) prefix-sum chunks -> Gp
  k_prefix<<<dim3(128, 1, NBATCH), 256, 0, stream>>>(Gc, Gp);

  // 6) fitfused: fit = Gp_i . F1T^T + xb_blk . Sd^T
  k_gemm<3><<<dim3(16, 1, NBATCH), 512, 0, stream>>>(
      Gp, Fcat, xb, Sd, nullptr, nullptr, fit);

  // 7) finalize
  finalize_kernel<<<NBATCH * EMB, 256, 0, stream>>>(xb, fit, out);
}